// Round 1
// baseline (132.717 us; speedup 1.0000x reference)
//
#include <hip/hip_runtime.h>
#include <hip/hip_bf16.h>
#include <stdint.h>

#define NN 8192
#define FF 256

typedef unsigned short u16;
typedef __attribute__((ext_vector_type(4))) float f32x4;
typedef __attribute__((ext_vector_type(8))) short s16x8;
typedef __attribute__((ext_vector_type(8))) __bf16 bf16x8;

// round-half-up f32->bf16 (cheap; bias negligible for this problem)
__device__ inline u16 bf_rhu(float f) {
  union { float f; unsigned u; } v; v.f = f;
  return (u16)((v.u + 0x8000u) >> 16);
}
// round-to-nearest-even f32->bf16
__device__ inline u16 f2bf_rne(float f) {
  union { float f; unsigned u; } v; v.f = f;
  unsigned r = v.u + 0x7FFFu + ((v.u >> 16) & 1u);
  return (u16)(r >> 16);
}

__device__ inline void gld_lds16(const void* g, void* l) {
  __builtin_amdgcn_global_load_lds(
      (const __attribute__((address_space(1))) void*)g,
      (__attribute__((address_space(3))) void*)l, 16, 0, 0);
}

// ---------------- K1: rowsum -> dis[i] = rsqrt(rowsum) ----------------
__global__ __launch_bounds__(256) void k_rowsum(const float* __restrict__ adj,
                                                float* __restrict__ dis) {
  const int row = blockIdx.x;
  const int t = threadIdx.x;
  const f32x4* p = reinterpret_cast<const f32x4*>(adj + (size_t)row * NN);
  float s = 0.f;
#pragma unroll
  for (int q = 0; q < 8; ++q) {
    f32x4 v = p[q * 256 + t];
    s += (v.x + v.y) + (v.z + v.w);
  }
#pragma unroll
  for (int o = 32; o > 0; o >>= 1) s += __shfl_down(s, o);
  __shared__ float red[4];
  if ((t & 63) == 0) red[t >> 6] = s;
  __syncthreads();
  if (t == 0) {
    float tot = (red[0] + red[1]) + (red[2] + red[3]);
    dis[row] = tot > 0.f ? 1.0f / sqrtf(tot) : 0.f;
  }
}

// ------- K2: xsT[f][j] = bf16(dis[j] * x[j][f])  (transposed, scaled) -------
__global__ __launch_bounds__(256) void k_xst(const float* __restrict__ x,
                                             const float* __restrict__ dis,
                                             u16* __restrict__ xsT) {
  __shared__ float tile[64][65];
  const int j0 = blockIdx.x * 64, f0 = blockIdx.y * 64;
  const int t = threadIdx.x;
  const int tr = t >> 4, tc = (t & 15) * 4;
#pragma unroll
  for (int q = 0; q < 4; ++q) {
    int r = q * 16 + tr;
    f32x4 v = *reinterpret_cast<const f32x4*>(x + (size_t)(j0 + r) * FF + f0 + tc);
    tile[r][tc] = v.x; tile[r][tc + 1] = v.y; tile[r][tc + 2] = v.z; tile[r][tc + 3] = v.w;
  }
  __syncthreads();
  float d[4];
#pragma unroll
  for (int e = 0; e < 4; ++e) d[e] = dis[j0 + tc + e];
#pragma unroll
  for (int q = 0; q < 4; ++q) {
    int fr = q * 16 + tr;
    ushort4 o;
    o.x = f2bf_rne(tile[tc + 0][fr] * d[0]);
    o.y = f2bf_rne(tile[tc + 1][fr] * d[1]);
    o.z = f2bf_rne(tile[tc + 2][fr] * d[2]);
    o.w = f2bf_rne(tile[tc + 3][fr] * d[3]);
    *reinterpret_cast<ushort4*>(xsT + (size_t)(f0 + fr) * NN + j0 + tc) = o;
  }
}

// ---------------- K2c: Wb = bf16(W), layout unchanged [o][f] ----------------
__global__ __launch_bounds__(256) void k_wb(const float* __restrict__ W,
                                            u16* __restrict__ Wb) {
  int idx = (blockIdx.x * 256 + threadIdx.x) * 4;
  f32x4 v = *reinterpret_cast<const f32x4*>(W + idx);
  ushort4 o;
  o.x = f2bf_rne(v.x); o.y = f2bf_rne(v.y); o.z = f2bf_rne(v.z); o.w = f2bf_rne(v.w);
  *reinterpret_cast<ushort4*>(Wb + idx) = o;
}

// -------- K3: split-K GEMM  part[kc][bm][128][256] = adj_tile @ xsT^T --------
// tile 128x256, BK=64, KC=4 (K=2048/block), 512 thr (8 waves, each 64x64)
__global__ __launch_bounds__(512, 2) void k_gemm1(const float* __restrict__ adj,
                                                  const u16* __restrict__ xsT,
                                                  float* __restrict__ part) {
  __shared__ __align__(16) u16 As[2][128 * 64];
  __shared__ __align__(16) u16 Bs[2][256 * 64];
  const int bm = blockIdx.x;            // 0..63
  const int kc = blockIdx.y;            // 0..3
  const size_t i0 = (size_t)bm * 128;
  const int k0 = kc * 2048;
  const int t = threadIdx.x;
  const int lane = t & 63;
  const int w = t >> 6;                 // 0..7
  const int wr = w >> 2;                // 0..1 (64 rows each)
  const int wc = w & 3;                 // 0..3 (64 cols each)

  f32x4 acc[4][4] = {};
  f32x4 areg[2][2];

  auto loadA = [&](int kt) {
#pragma unroll
    for (int q = 0; q < 2; ++q) {
      int cid = q * 512 + t;
      int r = cid >> 3, c = cid & 7;
      const float* g = adj + (i0 + r) * (size_t)NN + (k0 + kt * 64 + c * 8);
      areg[q][0] = *reinterpret_cast<const f32x4*>(g);
      areg[q][1] = *reinterpret_cast<const f32x4*>(g + 4);
    }
  };
  auto writeA = [&](int buf) {
#pragma unroll
    for (int q = 0; q < 2; ++q) {
      int cid = q * 512 + t;
      int r = cid >> 3, c = cid & 7;
      int slot = r * 8 + (c ^ (r & 7));   // XOR-swizzle (T2 / G4)
      s16x8 o;
#pragma unroll
      for (int e = 0; e < 4; ++e) o[e] = (short)bf_rhu(areg[q][0][e]);
#pragma unroll
      for (int e = 0; e < 4; ++e) o[4 + e] = (short)bf_rhu(areg[q][1][e]);
      *reinterpret_cast<s16x8*>(&As[buf][slot * 8]) = o;
    }
  };
  auto stageB = [&](int buf, int kt) {
#pragma unroll
    for (int q = 0; q < 4; ++q) {
      int s = (w * 4 + q) * 64 + lane;
      int r = s >> 3, pp = s & 7;
      int c = pp ^ (r & 7);               // inverse swizzle on global source
      const u16* g = xsT + (size_t)r * NN + (k0 + kt * 64 + c * 8);
      gld_lds16(g, &Bs[buf][(w * 4 + q) * 512]);
    }
  };
  auto compute = [&](int buf) {
#pragma unroll
    for (int kk = 0; kk < 2; ++kk) {
      const int cg = kk * 4 + (lane >> 4);
      bf16x8 af[4], bfv[4];
#pragma unroll
      for (int mi = 0; mi < 4; ++mi) {
        int r = wr * 64 + mi * 16 + (lane & 15);
        af[mi] = __builtin_bit_cast(bf16x8,
            *reinterpret_cast<const s16x8*>(&As[buf][(r * 8 + (cg ^ (r & 7))) * 8]));
      }
#pragma unroll
      for (int ni = 0; ni < 4; ++ni) {
        int r = wc * 64 + ni * 16 + (lane & 15);
        bfv[ni] = __builtin_bit_cast(bf16x8,
            *reinterpret_cast<const s16x8*>(&Bs[buf][(r * 8 + (cg ^ (r & 7))) * 8]));
      }
#pragma unroll
      for (int mi = 0; mi < 4; ++mi)
#pragma unroll
        for (int ni = 0; ni < 4; ++ni)
          acc[mi][ni] = __builtin_amdgcn_mfma_f32_16x16x32_bf16(af[mi], bfv[ni], acc[mi][ni], 0, 0, 0);
    }
  };

  loadA(0);
  stageB(0, 0);
  writeA(0);
  __syncthreads();
#pragma unroll 2
  for (int kt = 0; kt < 32; ++kt) {
    int buf = kt & 1;
    if (kt + 1 < 32) {
      loadA(kt + 1);
      stageB(buf ^ 1, kt + 1);
    }
    compute(buf);
    if (kt + 1 < 32) writeA(buf ^ 1);
    __syncthreads();
  }

  float* pout = part + ((size_t)kc * 64 + bm) * (128 * 256);
#pragma unroll
  for (int mi = 0; mi < 4; ++mi) {
    int rbase = wr * 64 + mi * 16 + ((lane >> 4) * 4);
#pragma unroll
    for (int ni = 0; ni < 4; ++ni) {
      int cc = wc * 64 + ni * 16 + (lane & 15);
#pragma unroll
      for (int e = 0; e < 4; ++e)
        pout[(size_t)(rbase + e) * 256 + cc] = acc[mi][ni][e];
    }
  }
}

// -------- K4: h[i][f] = bf16( dis[i] * sum_kc part ) --------
__global__ __launch_bounds__(256) void k_reduce(const float* __restrict__ part,
                                                const float* __restrict__ dis,
                                                u16* __restrict__ h) {
  size_t idx = ((size_t)blockIdx.x * 256 + threadIdx.x) * 4;
  int i = (int)(idx >> 8);
  const size_t stride = (size_t)64 * 128 * 256;
  f32x4 s = *reinterpret_cast<const f32x4*>(part + idx)
          + *reinterpret_cast<const f32x4*>(part + stride + idx)
          + *reinterpret_cast<const f32x4*>(part + 2 * stride + idx)
          + *reinterpret_cast<const f32x4*>(part + 3 * stride + idx);
  float d = dis[i];
  ushort4 o;
  o.x = f2bf_rne(s.x * d); o.y = f2bf_rne(s.y * d);
  o.z = f2bf_rne(s.z * d); o.w = f2bf_rne(s.w * d);
  *reinterpret_cast<ushort4*>(h + idx) = o;
}

// -------- K5: out = h @ W^T + b  (tile 64x128, BK=64) --------
__global__ __launch_bounds__(256) void k_gemm2(const u16* __restrict__ h,
                                               const u16* __restrict__ Wb,
                                               const float* __restrict__ bias,
                                               float* __restrict__ out) {
  __shared__ __align__(16) u16 As[2][64 * 64];
  __shared__ __align__(16) u16 Bs[2][128 * 64];
  const int bm = blockIdx.x;   // 0..127
  const int bn = blockIdx.y;   // 0..1
  const size_t i0 = (size_t)bm * 64;
  const int o0 = bn * 128;
  const int t = threadIdx.x, lane = t & 63, w = t >> 6;
  const int wr = w >> 1, wc = w & 1;

  f32x4 acc[2][4] = {};

  auto stageA = [&](int buf, int kt) {
#pragma unroll
    for (int q = 0; q < 2; ++q) {
      int s = (w * 2 + q) * 64 + lane;
      int r = s >> 3, pp = s & 7, c = pp ^ (r & 7);
      gld_lds16(h + (i0 + r) * FF + kt * 64 + c * 8, &As[buf][(w * 2 + q) * 512]);
    }
  };
  auto stageB = [&](int buf, int kt) {
#pragma unroll
    for (int q = 0; q < 4; ++q) {
      int s = (w * 4 + q) * 64 + lane;
      int r = s >> 3, pp = s & 7, c = pp ^ (r & 7);
      gld_lds16(Wb + (size_t)(o0 + r) * FF + kt * 64 + c * 8, &Bs[buf][(w * 4 + q) * 512]);
    }
  };
  auto compute = [&](int buf) {
#pragma unroll
    for (int kk = 0; kk < 2; ++kk) {
      int cg = kk * 4 + (lane >> 4);
      bf16x8 af[2], bfv[4];
#pragma unroll
      for (int mi = 0; mi < 2; ++mi) {
        int r = wr * 32 + mi * 16 + (lane & 15);
        af[mi] = __builtin_bit_cast(bf16x8,
            *reinterpret_cast<const s16x8*>(&As[buf][(r * 8 + (cg ^ (r & 7))) * 8]));
      }
#pragma unroll
      for (int ni = 0; ni < 4; ++ni) {
        int r = wc * 64 + ni * 16 + (lane & 15);
        bfv[ni] = __builtin_bit_cast(bf16x8,
            *reinterpret_cast<const s16x8*>(&Bs[buf][(r * 8 + (cg ^ (r & 7))) * 8]));
      }
#pragma unroll
      for (int mi = 0; mi < 2; ++mi)
#pragma unroll
        for (int ni = 0; ni < 4; ++ni)
          acc[mi][ni] = __builtin_amdgcn_mfma_f32_16x16x32_bf16(af[mi], bfv[ni], acc[mi][ni], 0, 0, 0);
    }
  };

  stageA(0, 0); stageB(0, 0);
  __syncthreads();
  for (int kt = 0; kt < 4; ++kt) {
    int buf = kt & 1;
    if (kt + 1 < 4) { stageA(buf ^ 1, kt + 1); stageB(buf ^ 1, kt + 1); }
    compute(buf);
    __syncthreads();
  }

  float bv[4];
#pragma unroll
  for (int ni = 0; ni < 4; ++ni) bv[ni] = bias[o0 + wc * 64 + ni * 16 + (lane & 15)];
#pragma unroll
  for (int mi = 0; mi < 2; ++mi) {
    int rbase = wr * 32 + mi * 16 + (lane >> 4) * 4;
#pragma unroll
    for (int ni = 0; ni < 4; ++ni) {
      int cc = o0 + wc * 64 + ni * 16 + (lane & 15);
#pragma unroll
      for (int e = 0; e < 4; ++e)
        out[(i0 + rbase + e) * FF + cc] = acc[mi][ni][e] + bv[ni];
    }
  }
}

extern "C" void kernel_launch(void* const* d_in, const int* in_sizes, int n_in,
                              void* d_out, int out_size, void* d_ws, size_t ws_size,
                              hipStream_t stream) {
  (void)in_sizes; (void)n_in; (void)out_size; (void)ws_size;
  const float* x   = (const float*)d_in[0];
  const float* adj = (const float*)d_in[1];
  const float* W   = (const float*)d_in[2];
  const float* b   = (const float*)d_in[3];
  float* out = (float*)d_out;
  char* ws = (char*)d_ws;

  // workspace layout (all 16B-aligned): dis 32KB | xsT 4MB | Wb 128KB | h 4MB | part 32MB
  float* dis = (float*)ws;
  u16* xsT   = (u16*)(ws + (32u << 10));
  u16* Wb    = (u16*)(ws + (32u << 10) + (4u << 20));
  u16* h     = (u16*)(ws + (32u << 10) + (4u << 20) + (128u << 10));
  float* part = (float*)(ws + (32u << 10) + (4u << 20) + (128u << 10) + (4u << 20));

  k_rowsum<<<dim3(8192), dim3(256), 0, stream>>>(adj, dis);
  k_xst<<<dim3(128, 4), dim3(256), 0, stream>>>(x, dis, xsT);
  k_wb<<<dim3(64), dim3(256), 0, stream>>>(W, Wb);
  k_gemm1<<<dim3(64, 4), dim3(512), 0, stream>>>(adj, xsT, part);
  k_reduce<<<dim3(2048), dim3(256), 0, stream>>>(part, dis, h);
  k_gemm2<<<dim3(128, 2), dim3(256), 0, stream>>>(h, Wb, b, out);
}